// Round 6
// baseline (18.338 us; speedup 1.0000x reference)
//
#include <hip/hip_runtime.h>
#include <math.h>

#define VOCAB 100
#define TT    128
#define BB    1024
#define MM    32
#define DQ    64
#define DV    64
#define BPB   4                 // batches per block (one 32-lane group each)
#define NTHR  512               // 16 groups x 32 lanes = 8 waves
#define NBLK  (BB / BPB)        // 256 blocks -> 1 per CU
#define CH    32                // t-chunk
#define NCH   (TT / CH)
#define ASTR  36                // att_l row stride: 16B-aligned, banks (4q+m)%32
#define PSTR  36                // pacc row stride [t2][m]

// Fully fused, 2-barrier kernel.
//  A (all 16 groups): qsv staging, Wa column -> regs, logits from GLOBAL Eq
//    (L1-resident; no LDS staging); waves 4-7 additionally compute sq/sv.
//  barrier1.
//  C: waves 0-1 convert w->sval (group-local); waves 2-3 transposed
//    register softmax (lane = q, zero cross-lane ops). Disjoint LDS.
//  barrier2.
//  D: scan on waves 0-1 (4 groups, 1 batch each), barrier-free, deferred
//    pred reduction via conflict-free pacc, direct global stores.
__global__ __launch_bounds__(NTHR) void dkvmn_fused(
    const int* __restrict__ questions,
    const int* __restrict__ answers,
    const float* __restrict__ Eq,
    const float* __restrict__ Ev,
    const float* __restrict__ Wa,
    const float* __restrict__ ba,
    const float* __restrict__ Wf,
    const float* __restrict__ bf,
    float* __restrict__ out) {

  __shared__ __align__(16) float att_l[VOCAB * ASTR];   // logits, then att
  __shared__ float sq_l[VOCAB];
  __shared__ float sv_l[VOCAB];
  __shared__ __align__(16) float2 qsv_l[BPB * TT];      // {q bits, w -> sval}
  __shared__ __align__(16) float big[BPB * CH * PSTR];  // pacc only

  const int tid = threadIdx.x;
  const int b0  = blockIdx.x * BPB;
  const int g   = tid >> 5;     // group 0..15
  const int m   = tid & 31;     // lane-in-group = memory slot

  // ---- A1: qsv staging (1 elem/thread; 4 consecutive b per t-row) ----
  {
    const int t = tid >> 2, j = tid & 3;
    const int gi = t * BB + b0 + j;
    int q = questions[gi];
    int a = answers[gi];
    int w = (q * 2 + a) % VOCAB;
    qsv_l[j * TT + t] = make_float2(__int_as_float(q), __int_as_float(w));
  }

  // ---- A2: Wa column for slot m -> registers (coalesced, L1/L2-hot) ----
  float wa[DQ];
  #pragma unroll
  for (int k = 0; k < DQ; ++k) wa[k] = Wa[k * MM + m];
  const float bam = ba[m];

  // ---- A3: logits, Eq straight from global (group-uniform row reads) ----
  for (int q = g; q < VOCAB; q += 16) {
    const float4* eq4 = (const float4*)(Eq + q * DQ);
    float ax = 0.f, ay = 0.f, az = 0.f, aw = 0.f;
    #pragma unroll
    for (int k4 = 0; k4 < DQ / 4; ++k4) {
      float4 e = eq4[k4];
      ax = fmaf(e.x, wa[4 * k4 + 0], ax);
      ay = fmaf(e.y, wa[4 * k4 + 1], ay);
      az = fmaf(e.z, wa[4 * k4 + 2], az);
      aw = fmaf(e.w, wa[4 * k4 + 3], aw);
    }
    att_l[q * ASTR + m] = (ax + ay) + (az + aw) + bam;
  }

  // ---- A4 (waves 4-7): sq / sv scalar tables from global ----
  if (tid >= 256 && tid < 256 + VOCAB) {
    const int v = tid - 256;
    const float4* eq4 = (const float4*)(Eq + v * DQ);
    const float4* wfq = (const float4*)Wf;
    float s = 0.f;
    #pragma unroll
    for (int k4 = 0; k4 < DQ / 4; ++k4) {
      float4 e = eq4[k4], w = wfq[k4];
      s = fmaf(e.x, w.x, fmaf(e.y, w.y, fmaf(e.z, w.z, fmaf(e.w, w.w, s))));
    }
    sq_l[v] = s + bf[0];
  } else if (tid >= 356 && tid < 356 + VOCAB) {
    const int v = tid - 356;
    const float4* ev4 = (const float4*)(Ev + v * DV);
    const float4* wfr = (const float4*)(Wf + DQ);
    float s = 0.f;
    #pragma unroll
    for (int k4 = 0; k4 < DV / 4; ++k4) {
      float4 e = ev4[k4], w = wfr[k4];
      s = fmaf(e.x, w.x, fmaf(e.y, w.y, fmaf(e.z, w.z, fmaf(e.w, w.w, s))));
    }
    sv_l[v] = s;
  }

  __syncthreads();   // (1) logits + sq/sv + qsv staged

  if (tid < 128) {
    // ---- C1 (waves 0-1): group-local w -> sval conversion ----
    const int j = tid >> 5;
    #pragma unroll
    for (int r = 0; r < 4; ++r) {
      const int t = m + 32 * r;
      float2 x = qsv_l[j * TT + t];
      x.y = sv_l[__float_as_int(x.y)];
      qsv_l[j * TT + t] = x;
    }
  } else if (tid < 128 + VOCAB + 28 && tid - 128 < VOCAB) {
    // ---- C2 (waves 2-3): transposed register softmax, lane = q ----
    const int q = tid - 128;
    float4* row = (float4*)(att_l + q * ASTR);
    float v[MM];
    #pragma unroll
    for (int jj = 0; jj < 8; ++jj) {
      float4 x = row[jj];
      v[4 * jj + 0] = x.x; v[4 * jj + 1] = x.y;
      v[4 * jj + 2] = x.z; v[4 * jj + 3] = x.w;
    }
    float mx = v[0];
    #pragma unroll
    for (int k = 1; k < MM; ++k) mx = fmaxf(mx, v[k]);
    float sm = 0.f;
    #pragma unroll
    for (int k = 0; k < MM; ++k) { v[k] = __expf(v[k] - mx); sm += v[k]; }
    const float inv = __builtin_amdgcn_rcpf(sm);
    #pragma unroll
    for (int jj = 0; jj < 8; ++jj)
      row[jj] = make_float4(v[4 * jj + 0] * inv, v[4 * jj + 1] * inv,
                            v[4 * jj + 2] * inv, v[4 * jj + 3] * inv);
  }

  __syncthreads();   // (2) att + qsv final

  // ---- D: scan (groups 0-3 = waves 0-1), barrier-free ----
  if (tid < 128) {
    const int j = tid >> 5;
    float rvec = 0.f;
    const float2* qsv_g = qsv_l + j * TT;
    float* pacc = big + j * (CH * PSTR);

    for (int c = 0; c < NCH; ++c) {
      const float4* x4 = (const float4*)(qsv_g + c * CH);  // 2 steps / b128
      #pragma unroll
      for (int h = 0; h < CH / 2; ++h) {
        float4 x = x4[h];
        int q0 = __float_as_int(x.x);
        float av0 = att_l[q0 * ASTR + m];          // banks (4q+m): c-free
        pacc[(2 * h + 0) * PSTR + m] = av0 * rvec; // banks (4t2+m): c-free
        rvec = fmaf(av0, x.y, rvec);               // loop-carried dep #1
        int q1 = __float_as_int(x.z);
        float av1 = att_l[q1 * ASTR + m];
        pacc[(2 * h + 1) * PSTR + m] = av1 * rvec;
        rvec = fmaf(av1, x.w, rvec);               // loop-carried dep #2
      }
      // reduce: lane m owns t2 = m; 8x b128, lanes 0-7 span all 32 banks
      const float4* prow = (const float4*)(pacc + m * PSTR);
      float s = 0.f;
      #pragma unroll
      for (int jj = 0; jj < 8; ++jj) {
        float4 r = prow[jj];
        s += (r.x + r.y) + (r.z + r.w);
      }
      const int t = c * CH + m;
      const int q = __float_as_int(qsv_g[t].x);
      out[t * BB + b0 + j] = s + sq_l[q];
    }
  }
}

extern "C" void kernel_launch(void* const* d_in, const int* in_sizes, int n_in,
                              void* d_out, int out_size, void* d_ws, size_t ws_size,
                              hipStream_t stream) {
  const int*   questions = (const int*)d_in[0];
  const int*   answers   = (const int*)d_in[1];
  const float* Eq = (const float*)d_in[2];
  const float* Ev = (const float*)d_in[3];
  const float* Wa = (const float*)d_in[4];
  const float* ba = (const float*)d_in[5];
  const float* Wf = (const float*)d_in[6];
  const float* bf = (const float*)d_in[7];
  float* out = (float*)d_out;

  hipLaunchKernelGGL(dkvmn_fused, dim3(NBLK), dim3(NTHR), 0, stream,
                     questions, answers, Eq, Ev, Wa, ba, Wf, bf, out);
}

// Round 7
// 16.588 us; speedup vs baseline: 1.1055x; 1.1055x over previous
//
#include <hip/hip_runtime.h>
#include <math.h>

#define VOCAB 100
#define TT    128
#define BB    1024
#define MM    32
#define DQ    64
#define DV    64
#define BPB   4                 // batches per block (one 32-lane group each)
#define NTHR  256               // 8 groups x 32 lanes = 4 waves
#define NBLK  (BB / BPB)        // 256 blocks -> 1 per CU
#define CH    32                // t-chunk
#define NCH   (TT / CH)
#define ASTR  36                // att_l row stride: 16B-aligned, banks (4q+m)%32
#define PSTR  36                // pacc row stride [t2][m]
#define BIGSZ (VOCAB * DQ)      // 6400 floats: Eq stage; pacc reuses 4608 of it

// R5's table structure (measured fast) + R6's scan halving (256 blocks).
//  A: stage Eq->LDS, qsv staging, Wa column -> regs.    barrier.
//  B: logits; even waves read Eq from LDS, odd from global (two pipes).
//     barrier.
//  C: waves 0-1 transposed register softmax (lane=q, zero cross-lane);
//     waves 2-3 sq/sv tables (Eq from LDS, Ev from global).   barrier.
//  w->sval conversion (all threads).                     barrier.
//  D: scan on waves 0-1 (4 groups, 1 batch each), barrier-free, deferred
//     reduction in conflict-free pacc, direct global stores. Waves 2-3 exit.
__global__ __launch_bounds__(NTHR) void dkvmn_fused(
    const int* __restrict__ questions,
    const int* __restrict__ answers,
    const float* __restrict__ Eq,
    const float* __restrict__ Ev,
    const float* __restrict__ Wa,
    const float* __restrict__ ba,
    const float* __restrict__ Wf,
    const float* __restrict__ bf,
    float* __restrict__ out) {

  __shared__ __align__(16) float att_l[VOCAB * ASTR];   // logits, then att
  __shared__ float sq_l[VOCAB];
  __shared__ float sv_l[VOCAB];
  __shared__ __align__(16) float wf_l[2 * DQ + 1];      // Wf_q | Wf_r | bf
  __shared__ __align__(16) float2 qsv_l[BPB * TT];      // {q bits, w -> sval}
  __shared__ __align__(16) float big[BIGSZ];            // Eq stage / pacc

  const int tid = threadIdx.x;
  const int b0  = blockIdx.x * BPB;
  const int g   = tid >> 5;     // group 0..7
  const int m   = tid & 31;     // lane-in-group = memory slot

  // ---- A1: stage Eq -> big (coalesced b128) ----
  {
    const float4* Eq4 = (const float4*)Eq;
    float4* dst = (float4*)big;
    #pragma unroll
    for (int it = 0; it < 7; ++it) {
      int i = tid + it * NTHR;
      if (i < VOCAB * DQ / 4) dst[i] = Eq4[i];
    }
  }
  if (tid < 2 * DQ) wf_l[tid] = Wf[tid];
  if (tid == NTHR - 1) wf_l[2 * DQ] = bf[0];

  // ---- A2: qsv staging ----
  #pragma unroll
  for (int it = 0; it < 2; ++it) {
    int idx = tid + it * NTHR;          // < 512 = TT*BPB
    int t = idx >> 2, j = idx & 3;
    int gi = t * BB + b0 + j;
    int q = questions[gi];
    int a = answers[gi];
    int w = (q * 2 + a) % VOCAB;
    qsv_l[j * TT + t] = make_float2(__int_as_float(q), __int_as_float(w));
  }

  // ---- A3: Wa column for slot m -> registers ----
  float wa[DQ];
  #pragma unroll
  for (int k = 0; k < DQ; ++k) wa[k] = Wa[k * MM + m];
  const float bam = ba[m];

  __syncthreads();   // (1) staging done

  // ---- B: raw logits; even waves via LDS, odd via global (split pipes) ----
  if ((tid >> 6) & 1) {
    for (int q = g; q < VOCAB; q += 8) {
      const float4* eq4 = (const float4*)(Eq + q * DQ);
      float ax = 0.f, ay = 0.f, az = 0.f, aw = 0.f;
      #pragma unroll
      for (int k4 = 0; k4 < DQ / 4; ++k4) {
        float4 e = eq4[k4];
        ax = fmaf(e.x, wa[4 * k4 + 0], ax);
        ay = fmaf(e.y, wa[4 * k4 + 1], ay);
        az = fmaf(e.z, wa[4 * k4 + 2], az);
        aw = fmaf(e.w, wa[4 * k4 + 3], aw);
      }
      att_l[q * ASTR + m] = (ax + ay) + (az + aw) + bam;
    }
  } else {
    for (int q = g; q < VOCAB; q += 8) {
      const float4* eq4 = (const float4*)(big + q * DQ);
      float ax = 0.f, ay = 0.f, az = 0.f, aw = 0.f;
      #pragma unroll
      for (int k4 = 0; k4 < DQ / 4; ++k4) {
        float4 e = eq4[k4];
        ax = fmaf(e.x, wa[4 * k4 + 0], ax);
        ay = fmaf(e.y, wa[4 * k4 + 1], ay);
        az = fmaf(e.z, wa[4 * k4 + 2], az);
        aw = fmaf(e.w, wa[4 * k4 + 3], aw);
      }
      att_l[q * ASTR + m] = (ax + ay) + (az + aw) + bam;
    }
  }

  __syncthreads();   // (2) logits ready

  // ---- C: waves 0-1 transposed register softmax; waves 2-3 sq/sv ----
  if (tid < 128) {
    if (tid < VOCAB) {
      const int q = tid;
      float4* row = (float4*)(att_l + q * ASTR);
      float v[MM];
      #pragma unroll
      for (int jj = 0; jj < 8; ++jj) {
        float4 x = row[jj];
        v[4 * jj + 0] = x.x; v[4 * jj + 1] = x.y;
        v[4 * jj + 2] = x.z; v[4 * jj + 3] = x.w;
      }
      float mx = v[0];
      #pragma unroll
      for (int k = 1; k < MM; ++k) mx = fmaxf(mx, v[k]);
      float sm = 0.f;
      #pragma unroll
      for (int k = 0; k < MM; ++k) { v[k] = __expf(v[k] - mx); sm += v[k]; }
      const float inv = __builtin_amdgcn_rcpf(sm);
      #pragma unroll
      for (int jj = 0; jj < 8; ++jj)
        row[jj] = make_float4(v[4 * jj + 0] * inv, v[4 * jj + 1] * inv,
                              v[4 * jj + 2] * inv, v[4 * jj + 3] * inv);
    }
  } else if (tid - 128 < VOCAB) {
    const int v = tid - 128;
    const float4* eq4 = (const float4*)(big + v * DQ);
    const float4* wfq = (const float4*)wf_l;
    float s = 0.f;
    #pragma unroll
    for (int k4 = 0; k4 < DQ / 4; ++k4) {
      float4 e = eq4[k4], w = wfq[k4];
      s = fmaf(e.x, w.x, fmaf(e.y, w.y, fmaf(e.z, w.z, fmaf(e.w, w.w, s))));
    }
    sq_l[v] = s + wf_l[2 * DQ];
    const float4* ev4 = (const float4*)Ev + v * (DV / 4);
    const float4* wfr = (const float4*)(wf_l + DQ);
    float s2 = 0.f;
    #pragma unroll
    for (int k4 = 0; k4 < DV / 4; ++k4) {
      float4 e = ev4[k4], w = wfr[k4];
      s2 = fmaf(e.x, w.x, fmaf(e.y, w.y, fmaf(e.z, w.z, fmaf(e.w, w.w, s2))));
    }
    sv_l[v] = s2;
  }

  __syncthreads();   // (3) att + sq/sv ready

  // ---- w -> sval conversion (all threads; Eq staging now dead) ----
  #pragma unroll
  for (int it = 0; it < 2; ++it) {
    int idx = tid + it * NTHR;
    int t = idx >> 2, j = idx & 3;
    float2 x = qsv_l[j * TT + t];
    x.y = sv_l[__float_as_int(x.y)];
    qsv_l[j * TT + t] = x;
  }
  __syncthreads();   // (4) qsv final; big becomes pacc

  // ---- D: scan on waves 0-1 (1 batch per group), barrier-free ----
  if (tid < 128) {
    const int j = tid >> 5;     // local batch 0..3
    float rvec = 0.f;
    const float2* qsv_g = qsv_l + j * TT;
    float* pacc = big + j * (CH * PSTR);

    for (int c = 0; c < NCH; ++c) {
      const float4* x4 = (const float4*)(qsv_g + c * CH);  // 2 steps / b128
      #pragma unroll
      for (int h = 0; h < CH / 2; ++h) {
        float4 x = x4[h];
        int q0 = __float_as_int(x.x);
        float av0 = att_l[q0 * ASTR + m];          // banks (4q+m): c-free
        pacc[(2 * h + 0) * PSTR + m] = av0 * rvec; // banks (4t2+m): c-free
        rvec = fmaf(av0, x.y, rvec);               // loop-carried dep #1
        int q1 = __float_as_int(x.z);
        float av1 = att_l[q1 * ASTR + m];
        pacc[(2 * h + 1) * PSTR + m] = av1 * rvec;
        rvec = fmaf(av1, x.w, rvec);               // loop-carried dep #2
      }
      // reduce: lane m owns t2 = m; 8x b128 per lane spans all banks
      const float4* prow = (const float4*)(pacc + m * PSTR);
      float s = 0.f;
      #pragma unroll
      for (int jj = 0; jj < 8; ++jj) {
        float4 r = prow[jj];
        s += (r.x + r.y) + (r.z + r.w);
      }
      const int t = c * CH + m;
      const int q = __float_as_int(qsv_g[t].x);
      out[t * BB + b0 + j] = s + sq_l[q];
    }
  }
}

extern "C" void kernel_launch(void* const* d_in, const int* in_sizes, int n_in,
                              void* d_out, int out_size, void* d_ws, size_t ws_size,
                              hipStream_t stream) {
  const int*   questions = (const int*)d_in[0];
  const int*   answers   = (const int*)d_in[1];
  const float* Eq = (const float*)d_in[2];
  const float* Ev = (const float*)d_in[3];
  const float* Wa = (const float*)d_in[4];
  const float* ba = (const float*)d_in[5];
  const float* Wf = (const float*)d_in[6];
  const float* bf = (const float*)d_in[7];
  float* out = (float*)d_out;

  hipLaunchKernelGGL(dkvmn_fused, dim3(NBLK), dim3(NTHR), 0, stream,
                     questions, answers, Eq, Ev, Wa, ba, Wf, bf, out);
}

// Round 8
// 16.435 us; speedup vs baseline: 1.1158x; 1.0093x over previous
//
#include <hip/hip_runtime.h>
#include <math.h>

#define VOCAB 100
#define TT    128
#define BB    1024
#define MM    32
#define DQ    64
#define DV    64
#define BPB   4                 // batches per block (one 32-lane group each)
#define NTHR  256               // 8 groups x 32 lanes = 4 waves
#define NBLK  (BB / BPB)        // 256 blocks -> 1 per CU
#define CH    32                // t-chunk
#define NCH   (TT / CH)
#define ASTR  36                // att_l row stride: 16B-aligned, banks (4q+m)%32
#define PSTR  36                // pacc row stride [t2][m]
#define BIGSZ (VOCAB * DQ)      // 6400 floats: Eq stage; pacc reuses 4608 of it

// 3-barrier fused kernel (R7 minus the w->sval pass/barrier, minus wf_l).
//  A: stage Eq->LDS, qsv staging, Wa column -> regs.            barrier 1.
//  B: logits; even waves read Eq from LDS, odd from global.     barrier 2.
//  C: waves 0-1 transposed register softmax (lane=q, no cross-lane ops);
//     waves 2-3 sq/sv tables (Eq from LDS, Ev/Wf/bf global).    barrier 3.
//  D: scan on waves 0-1; each group first self-converts its own qsv rows
//     (group-local, intra-wave lgkmcnt ordering -> no barrier), then scans
//     barrier-free with deferred pred reduction; direct global stores.
__global__ __launch_bounds__(NTHR) void dkvmn_fused(
    const int* __restrict__ questions,
    const int* __restrict__ answers,
    const float* __restrict__ Eq,
    const float* __restrict__ Ev,
    const float* __restrict__ Wa,
    const float* __restrict__ ba,
    const float* __restrict__ Wf,
    const float* __restrict__ bf,
    float* __restrict__ out) {

  __shared__ __align__(16) float att_l[VOCAB * ASTR];   // logits, then att
  __shared__ float sq_l[VOCAB];
  __shared__ float sv_l[VOCAB];
  __shared__ __align__(16) float2 qsv_l[BPB * TT];      // {q bits, w -> sval}
  __shared__ __align__(16) float big[BIGSZ];            // Eq stage / pacc

  const int tid = threadIdx.x;
  const int b0  = blockIdx.x * BPB;
  const int g   = tid >> 5;     // group 0..7
  const int m   = tid & 31;     // lane-in-group = memory slot

  // ---- A1: stage Eq -> big (coalesced b128) ----
  {
    const float4* Eq4 = (const float4*)Eq;
    float4* dst = (float4*)big;
    #pragma unroll
    for (int it = 0; it < 7; ++it) {
      int i = tid + it * NTHR;
      if (i < VOCAB * DQ / 4) dst[i] = Eq4[i];
    }
  }

  // ---- A2: qsv staging ----
  #pragma unroll
  for (int it = 0; it < 2; ++it) {
    int idx = tid + it * NTHR;          // < 512 = TT*BPB
    int t = idx >> 2, j = idx & 3;
    int gi = t * BB + b0 + j;
    int q = questions[gi];
    int a = answers[gi];
    int w = (q * 2 + a) % VOCAB;
    qsv_l[j * TT + t] = make_float2(__int_as_float(q), __int_as_float(w));
  }

  // ---- A3: Wa column for slot m -> registers ----
  float wa[DQ];
  #pragma unroll
  for (int k = 0; k < DQ; ++k) wa[k] = Wa[k * MM + m];
  const float bam = ba[m];

  __syncthreads();   // (1) staging done

  // ---- B: raw logits; even waves via LDS, odd via global (split pipes) ----
  if ((tid >> 6) & 1) {
    for (int q = g; q < VOCAB; q += 8) {
      const float4* eq4 = (const float4*)(Eq + q * DQ);
      float ax = 0.f, ay = 0.f, az = 0.f, aw = 0.f;
      #pragma unroll
      for (int k4 = 0; k4 < DQ / 4; ++k4) {
        float4 e = eq4[k4];
        ax = fmaf(e.x, wa[4 * k4 + 0], ax);
        ay = fmaf(e.y, wa[4 * k4 + 1], ay);
        az = fmaf(e.z, wa[4 * k4 + 2], az);
        aw = fmaf(e.w, wa[4 * k4 + 3], aw);
      }
      att_l[q * ASTR + m] = (ax + ay) + (az + aw) + bam;
    }
  } else {
    for (int q = g; q < VOCAB; q += 8) {
      const float4* eq4 = (const float4*)(big + q * DQ);
      float ax = 0.f, ay = 0.f, az = 0.f, aw = 0.f;
      #pragma unroll
      for (int k4 = 0; k4 < DQ / 4; ++k4) {
        float4 e = eq4[k4];
        ax = fmaf(e.x, wa[4 * k4 + 0], ax);
        ay = fmaf(e.y, wa[4 * k4 + 1], ay);
        az = fmaf(e.z, wa[4 * k4 + 2], az);
        aw = fmaf(e.w, wa[4 * k4 + 3], aw);
      }
      att_l[q * ASTR + m] = (ax + ay) + (az + aw) + bam;
    }
  }

  __syncthreads();   // (2) logits ready

  // ---- C: waves 0-1 transposed register softmax; waves 2-3 sq/sv ----
  if (tid < 128) {
    if (tid < VOCAB) {
      const int q = tid;
      float4* row = (float4*)(att_l + q * ASTR);
      float v[MM];
      #pragma unroll
      for (int jj = 0; jj < 8; ++jj) {
        float4 x = row[jj];
        v[4 * jj + 0] = x.x; v[4 * jj + 1] = x.y;
        v[4 * jj + 2] = x.z; v[4 * jj + 3] = x.w;
      }
      float mx = v[0];
      #pragma unroll
      for (int k = 1; k < MM; ++k) mx = fmaxf(mx, v[k]);
      float sm = 0.f;
      #pragma unroll
      for (int k = 0; k < MM; ++k) { v[k] = __expf(v[k] - mx); sm += v[k]; }
      const float inv = __builtin_amdgcn_rcpf(sm);
      #pragma unroll
      for (int jj = 0; jj < 8; ++jj)
        row[jj] = make_float4(v[4 * jj + 0] * inv, v[4 * jj + 1] * inv,
                              v[4 * jj + 2] * inv, v[4 * jj + 3] * inv);
    }
  } else if (tid - 128 < VOCAB) {
    const int v = tid - 128;
    const float4* eq4 = (const float4*)(big + v * DQ);
    const float4* wfq = (const float4*)Wf;            // wave-uniform rows
    float s = 0.f;
    #pragma unroll
    for (int k4 = 0; k4 < DQ / 4; ++k4) {
      float4 e = eq4[k4], w = wfq[k4];
      s = fmaf(e.x, w.x, fmaf(e.y, w.y, fmaf(e.z, w.z, fmaf(e.w, w.w, s))));
    }
    sq_l[v] = s + bf[0];
    const float4* ev4 = (const float4*)Ev + v * (DV / 4);
    const float4* wfr = (const float4*)(Wf + DQ);
    float s2 = 0.f;
    #pragma unroll
    for (int k4 = 0; k4 < DV / 4; ++k4) {
      float4 e = ev4[k4], w = wfr[k4];
      s2 = fmaf(e.x, w.x, fmaf(e.y, w.y, fmaf(e.z, w.z, fmaf(e.w, w.w, s2))));
    }
    sv_l[v] = s2;
  }

  __syncthreads();   // (3) att + sq/sv ready; big becomes pacc

  // ---- D: scan on waves 0-1 (1 batch per group), barrier-free ----
  if (tid < 128) {
    const int j = tid >> 5;     // local batch 0..3

    // self-convert this group's qsv rows: w -> sval (group-local; the same
    // wave reads these below -> compiler lgkmcnt ordering, no s_barrier)
    #pragma unroll
    for (int r = 0; r < 4; ++r) {
      const int t = 32 * r + m;
      float2 x = qsv_l[j * TT + t];
      x.y = sv_l[__float_as_int(x.y)];
      qsv_l[j * TT + t] = x;
    }

    float rvec = 0.f;
    const float2* qsv_g = qsv_l + j * TT;
    float* pacc = big + j * (CH * PSTR);

    for (int c = 0; c < NCH; ++c) {
      const float4* x4 = (const float4*)(qsv_g + c * CH);  // 2 steps / b128
      #pragma unroll
      for (int h = 0; h < CH / 2; ++h) {
        float4 x = x4[h];
        int q0 = __float_as_int(x.x);
        float av0 = att_l[q0 * ASTR + m];          // banks (4q+m): c-free
        pacc[(2 * h + 0) * PSTR + m] = av0 * rvec; // banks (4t2+m): c-free
        rvec = fmaf(av0, x.y, rvec);               // loop-carried dep #1
        int q1 = __float_as_int(x.z);
        float av1 = att_l[q1 * ASTR + m];
        pacc[(2 * h + 1) * PSTR + m] = av1 * rvec;
        rvec = fmaf(av1, x.w, rvec);               // loop-carried dep #2
      }
      // reduce: lane m owns t2 = m; 8x b128 per lane spans all banks
      const float4* prow = (const float4*)(pacc + m * PSTR);
      float s = 0.f;
      #pragma unroll
      for (int jj = 0; jj < 8; ++jj) {
        float4 r = prow[jj];
        s += (r.x + r.y) + (r.z + r.w);
      }
      const int t = c * CH + m;
      const int q = __float_as_int(qsv_g[t].x);
      out[t * BB + b0 + j] = s + sq_l[q];
    }
  }
}

extern "C" void kernel_launch(void* const* d_in, const int* in_sizes, int n_in,
                              void* d_out, int out_size, void* d_ws, size_t ws_size,
                              hipStream_t stream) {
  const int*   questions = (const int*)d_in[0];
  const int*   answers   = (const int*)d_in[1];
  const float* Eq = (const float*)d_in[2];
  const float* Ev = (const float*)d_in[3];
  const float* Wa = (const float*)d_in[4];
  const float* ba = (const float*)d_in[5];
  const float* Wf = (const float*)d_in[6];
  const float* bf = (const float*)d_in[7];
  float* out = (float*)d_out;

  hipLaunchKernelGGL(dkvmn_fused, dim3(NBLK), dim3(NTHR), 0, stream,
                     questions, answers, Eq, Ev, Wa, ba, Wf, bf, out);
}